// Round 5
// baseline (185.109 us; speedup 1.0000x reference)
//
#include <hip/hip_runtime.h>
#include <math.h>

#define M 64
#define NSEG 16
#define NS 2                 // i-split: 2 blocks per sample, 32-deep each

#define STAGE_TABLES()                                                            \
    if (t < 8) {                                                                  \
        float wv[NSEG + 1];                                                       \
        float ssum = 0.f;                                                         \
        _Pragma("unroll")                                                         \
        for (int i = 0; i <= NSEG; ++i) { wv[i] = fabsf(fw[t*(NSEG+1)+i]); ssum += wv[i]; } \
        const float inv = 1.0f / ssum;                                            \
        _Pragma("unroll")                                                         \
        for (int i = 0; i <= NSEG; ++i) wv[i] *= inv;                             \
        float csum = 0.f;                                                         \
        _Pragma("unroll")                                                         \
        for (int i = 0; i <= NSEG; ++i) {                                         \
            csum += wv[i];                                                        \
            cw_s[t][i] = make_float2(csum, wv[i < NSEG ? i + 1 : NSEG]);          \
        }                                                                         \
    }

#define STAGE_INPUTS()                                                            \
    if (t < M) {                                                                  \
        att_s[t] = attn[n * M + t];                                               \
        const float xa = boxes[n*4*M + 0*M + t];                                  \
        const float ya = boxes[n*4*M + 1*M + t];                                  \
        const float xb = boxes[n*4*M + 2*M + t];                                  \
        const float yb = boxes[n*4*M + 3*M + t];                                  \
        x1_s[t] = xa; y1_s[t] = ya; x2_s[t] = xb; y2_s[t] = yb;                   \
        area_s[t] = fmaxf(xb - xa, 0.f) * fmaxf(yb - ya, 0.f);                    \
    }

#define PAIR_GEOM(j_, k_)                                                         \
    const float rel  = att_s[j_] * att_s[k_];                                     \
    const float mx = fmaxf(x1_s[j_], x1_s[k_]);                                   \
    const float my = fmaxf(y1_s[j_], y1_s[k_]);                                   \
    const float Mx = fminf(x2_s[j_], x2_s[k_]);                                   \
    const float My = fminf(y2_s[j_], y2_s[k_]);                                   \
    const float inter = fmaxf(Mx - mx, 0.f) * fmaxf(My - my, 0.f);                \
    const float iou  = inter / (area_s[j_] + area_s[k_] - inter + 1e-12f);        \
    const float dist = 1.0f - iou;

// ---------------- Fused kernel: partials + last-block-per-sample finish ----------------
__global__ __launch_bounds__(1024, 4)
void fused_kernel(const float* __restrict__ boxes,
                  const float* __restrict__ attn,
                  const float* __restrict__ fw,
                  float4* __restrict__ ws4,
                  unsigned int* __restrict__ cnt,
                  float* __restrict__ out)
{
    __shared__ float2 cw_s[8][NSEG + 1];
    __shared__ float att_s[M];
    __shared__ float x1_s[M], y1_s[M], x2_s[M], y2_s[M], area_s[M];
    __shared__ float buf_s[M * M];        // ds during partials, sim during finish
    __shared__ float invrs_s[M];
    __shared__ float redA_s[16], redB_s[16], redC_s[16];
    __shared__ float bcast_s[3];
    __shared__ int flag_s;

    const int n = blockIdx.x;
    const int s = blockIdx.y;
    const int t = threadIdx.x;

    STAGE_TABLES();
    STAGE_INPUTS();
    __syncthreads();

    // plin for args guaranteed in [0,1]: trunc==floor, no clamps needed
    auto plin = [&](int kk, float x) -> float {
        const float y = 16.0f * x;
        const float fi = floorf(y);
        const int idx = (int)fi;
        const float2 cw = cw_s[kk][idx];
        return cw.x + (y - fi) * cw.y;
    };
    // f2(1-d): y may be -eps if d=1+ulp; trunc (idx) vs floor (frac) exactly as reference
    auto plin2d = [&](float d) -> float {
        const float y = fmaf(-16.0f, d, 16.0f);
        int idx = (int)y;                 // trunc: (-eps) -> 0, in-bounds
        const float fr = y - floorf(y);   // floor: matches reference frac
        const float2 cw = cw_s[2][idx];
        return cw.x + fr * cw.y;
    };

    // ---- Pass 1: dedup_score matrix + dist-conf partial (folded) ----
    float dc_local = 0.f;
    for (int p = t; p < M * M; p += 1024) {
        const int j = p >> 6, k = p & (M - 1);
        PAIR_GEOM(j, k);
        buf_s[p] = plin(3, rel) * plin(4, dist);
        dc_local += fabsf(plin(6, dist) - 0.5f);
    }
    const float ac_local = (t < M) ? fabsf(plin(5, att_s[t]) - 0.5f) : 0.f;
    {
        float vA = dc_local, vB = ac_local;
        #pragma unroll
        for (int off = 32; off > 0; off >>= 1) {
            vA += __shfl_down(vA, off, 64);
            vB += __shfl_down(vB, off, 64);
        }
        if ((t & 63) == 0) { redA_s[t >> 6] = vA; redB_s[t >> 6] = vB; }
    }
    __syncthreads();

    // ---- Pass 2: partial products over own 32-deep i-chunk ----
    {
        const int j = t >> 4;
        const int k0 = (t & 15) << 2;
        const int ibase = s * 32;
        float p0 = 1.f, p1 = 1.f, p2 = 1.f, p3 = 1.f;
        #pragma unroll
        for (int ii = 0; ii < 32; ++ii) {
            const int i = ibase + ii;
            const float aij = buf_s[i * M + j];
            const float4 kv = *(const float4*)&buf_s[i * M + k0];
            p0 *= plin2d(fabsf(aij - kv.x));
            p1 *= plin2d(fabsf(aij - kv.y));
            p2 *= plin2d(fabsf(aij - kv.z));
            p3 *= plin2d(fabsf(aij - kv.w));
        }
        ws4[(n * NS + s) * 1024 + t] = make_float4(p0, p1, p2, p3);
    }

    // ---- Fan-in: last-arriving block per sample finishes ----
    __threadfence();          // release our ws4 stores (device scope)
    __syncthreads();          // whole block's stores fenced
    if (t == 0) {
        const unsigned int old = atomicAdd(&cnt[n], 1u);
        // poison base 0xAAAAAAAA and zero are both even; we add exactly NS=2
        // per sample per call -> last arrival sees odd `old` under either base.
        flag_s = (int)(old & 1u);
    }
    __syncthreads();
    if (!flag_s) return;
    __threadfence();          // acquire partner's ws4 stores

    // ---- Finish: combine partials, apply att factor -> sim (overwrites buf_s) ----
    {
        const int j = t >> 4;
        const int k0 = (t & 15) << 2;
        const float4 v0 = ws4[(n * NS + 0) * 1024 + t];
        const float4 v1 = ws4[(n * NS + 1) * 1024 + t];
        const float aj = att_s[j];
        const float s0 = v0.x * v1.x * plin2d(fabsf(aj - att_s[k0 + 0]));
        const float s1 = v0.y * v1.y * plin2d(fabsf(aj - att_s[k0 + 1]));
        const float s2 = v0.z * v1.z * plin2d(fabsf(aj - att_s[k0 + 2]));
        const float s3 = v0.w * v1.w * plin2d(fabsf(aj - att_s[k0 + 3]));
        *(float4*)&buf_s[j * M + k0] = make_float4(s0, s1, s2, s3);
    }
    __syncthreads();

    // row sums -> invrs
    {
        const int j = t >> 4, c = t & 15;
        float psum = buf_s[j * M + c] + buf_s[j * M + c + 16] +
                     buf_s[j * M + c + 32] + buf_s[j * M + c + 48];
        #pragma unroll
        for (int off = 8; off > 0; off >>= 1) psum += __shfl_down(psum, off, 64);
        if (c == 0) invrs_s[j] = 1.0f / psum;
    }
    __syncthreads();

    // score pass: A computed on the fly (never materialized)
    float sc_local = 0.f;
    for (int p = t; p < M * M; p += 1024) {
        const int j = p >> 6, k = p & (M - 1);
        PAIR_GEOM(j, k);
        sc_local += plin(0, rel) * plin(1, dist) * (invrs_s[j] * invrs_s[k]);
    }
    if (t < M) sc_local += plin(0, att_s[t] * att_s[t]) * invrs_s[t];
    {
        float vC = sc_local;
        #pragma unroll
        for (int off = 32; off > 0; off >>= 1) vC += __shfl_down(vC, off, 64);
        if ((t & 63) == 0) redC_s[t >> 6] = vC;
    }
    __syncthreads();

    if (t == 0) {
        float score_sum = 0.f, dcs = 0.f, acs = 0.f;
        #pragma unroll
        for (int w = 0; w < 16; ++w) { score_sum += redC_s[w]; dcs += redA_s[w]; acs += redB_s[w]; }
        const float score = sqrtf(score_sum + 1e-20f);
        const float conf = plin(7, acs * (1.0f / M) + dcs * (1.0f / (M * M)));
        const float scc = fminf(fmaxf(score, 0.f), 10.0f);
        const float fl = floorf(scc);
        bcast_s[0] = conf; bcast_s[1] = fl; bcast_s[2] = scc - fl;
    }
    __syncthreads();

    if (t < 11) {
        const float conf = bcast_s[0];
        const int i0 = (int)bcast_s[1];
        const float frac = bcast_s[2];
        const int i1 = i0 > 10 ? 10 : i0;
        const int i2 = (i0 + 1) > 10 ? 10 : (i0 + 1);
        float v = 0.f;
        if (t == i1) v += 1.0f - frac;
        if (t == i2) v += frac;
        out[n * 11 + t] = v * conf;
    }
}

extern "C" void kernel_launch(void* const* d_in, const int* in_sizes, int n_in,
                              void* d_out, int out_size, void* d_ws, size_t ws_size,
                              hipStream_t stream) {
    const float* boxes = (const float*)d_in[0];   // (n,4,64) f32
    const float* attn  = (const float*)d_in[1];   // (n,64)   f32
    const float* fw    = (const float*)d_in[2];   // (16,17)  f32
    float* out = (float*)d_out;                   // (n,11)   f32
    const int n = in_sizes[1] / M;

    float4* ws4 = (float4*)d_ws;                              // n*NS*1024 float4 = 4 MB
    unsigned int* cnt = (unsigned int*)((char*)d_ws + (8u << 20));  // counters at +8 MB

    fused_kernel<<<dim3(n, NS), dim3(1024), 0, stream>>>(boxes, attn, fw, ws4, cnt, out);
}

// Round 6
// 77.944 us; speedup vs baseline: 2.3749x; 2.3749x over previous
//
#include <hip/hip_runtime.h>
#include <math.h>

#define M 64
#define NSEG 16
#define NS 4                 // i-split: 4 blocks per sample, 16-deep each (2 blocks/CU)

#define STAGE_TABLES()                                                            \
    if (t < 8) {                                                                  \
        float wv[NSEG + 1];                                                       \
        float ssum = 0.f;                                                         \
        _Pragma("unroll")                                                         \
        for (int i = 0; i <= NSEG; ++i) { wv[i] = fabsf(fw[t*(NSEG+1)+i]); ssum += wv[i]; } \
        const float inv = 1.0f / ssum;                                            \
        _Pragma("unroll")                                                         \
        for (int i = 0; i <= NSEG; ++i) wv[i] *= inv;                             \
        float csum = 0.f;                                                         \
        _Pragma("unroll")                                                         \
        for (int i = 0; i <= NSEG; ++i) {                                         \
            csum += wv[i];                                                        \
            cw_s[t][i] = make_float2(csum, wv[i < NSEG ? i + 1 : NSEG]);          \
        }                                                                         \
    }

#define STAGE_INPUTS()                                                            \
    if (t < M) {                                                                  \
        att_s[t] = attn[n * M + t];                                               \
        const float xa = boxes[n*4*M + 0*M + t];                                  \
        const float ya = boxes[n*4*M + 1*M + t];                                  \
        const float xb = boxes[n*4*M + 2*M + t];                                  \
        const float yb = boxes[n*4*M + 3*M + t];                                  \
        x1_s[t] = xa; y1_s[t] = ya; x2_s[t] = xb; y2_s[t] = yb;                   \
        area_s[t] = fmaxf(xb - xa, 0.f) * fmaxf(yb - ya, 0.f);                    \
    }

#define DEF_PLINS()                                                               \
    auto plin = [&](int kk, float x) -> float {                                   \
        const float y = 16.0f * x;                                                \
        const float fi = floorf(y);                                               \
        const int idx = (int)fi;                                                  \
        const float2 cw = cw_s[kk][idx];                                          \
        return cw.x + (y - fi) * cw.y;                                            \
    };                                                                            \
    auto plin2d = [&](float d) -> float {                                         \
        const float y = fmaf(-16.0f, d, 16.0f);                                   \
        int idx = (int)y;                 /* trunc: (-eps) -> 0, in-bounds */     \
        const float fr = y - floorf(y);   /* floor: matches reference frac */     \
        const float2 cw = cw_s[2][idx];                                           \
        return cw.x + fr * cw.y;                                                  \
    };

#define PAIR_GEOM(j_, k_)                                                         \
    const float rel  = att_s[j_] * att_s[k_];                                     \
    const float mx = fmaxf(x1_s[j_], x1_s[k_]);                                   \
    const float my = fmaxf(y1_s[j_], y1_s[k_]);                                   \
    const float Mx = fminf(x2_s[j_], x2_s[k_]);                                   \
    const float My = fminf(y2_s[j_], y2_s[k_]);                                   \
    const float inter = fmaxf(Mx - mx, 0.f) * fmaxf(My - my, 0.f);                \
    const float iou  = inter / (area_s[j_] + area_s[k_] - inter + 1e-12f);        \
    const float dist = 1.0f - iou;

// ---------------- Kernel 1: partial dedup products over a 16-deep i-chunk ----------------
__global__ __launch_bounds__(1024, 4)
void k1_partial(const float* __restrict__ boxes,
                const float* __restrict__ attn,
                const float* __restrict__ fw,
                float4* __restrict__ ws4)
{
    __shared__ float2 cw_s[8][NSEG + 1];
    __shared__ float att_s[M];
    __shared__ float x1_s[M], y1_s[M], x2_s[M], y2_s[M], area_s[M];
    __shared__ float ds_s[M * M];

    const int n = blockIdx.x;
    const int s = blockIdx.y;
    const int t = threadIdx.x;

    STAGE_TABLES();
    STAGE_INPUTS();
    __syncthreads();
    DEF_PLINS();

    // dedup_score matrix (full)
    for (int p = t; p < M * M; p += 1024) {
        const int j = p >> 6, k = p & (M - 1);
        PAIR_GEOM(j, k);
        ds_s[p] = plin(3, rel) * plin(4, dist);
    }
    __syncthreads();

    // one chunk per thread: j = t>>4, k0 = (t&15)*4; product over i in [16s, 16s+16)
    const int j = t >> 4;
    const int k0 = (t & 15) << 2;
    const int ibase = s * 16;
    float p0 = 1.f, p1 = 1.f, p2 = 1.f, p3 = 1.f;
    #pragma unroll
    for (int ii = 0; ii < 16; ++ii) {
        const int i = ibase + ii;
        const float aij = ds_s[i * M + j];
        const float4 kv = *(const float4*)&ds_s[i * M + k0];
        p0 *= plin2d(fabsf(aij - kv.x));
        p1 *= plin2d(fabsf(aij - kv.y));
        p2 *= plin2d(fabsf(aij - kv.z));
        p3 *= plin2d(fabsf(aij - kv.w));
    }
    ws4[(n * NS + s) * 1024 + t] = make_float4(p0, p1, p2, p3);
}

// ---------------- Kernel 2: combine partials, row sums, score, epilogue ----------------
__global__ __launch_bounds__(1024, 4)
void k2_finish(const float* __restrict__ boxes,
               const float* __restrict__ attn,
               const float* __restrict__ fw,
               const float4* __restrict__ ws4,
               float* __restrict__ out)
{
    __shared__ float2 cw_s[8][NSEG + 1];
    __shared__ float att_s[M];
    __shared__ float x1_s[M], y1_s[M], x2_s[M], y2_s[M], area_s[M];
    __shared__ float sim_s[M * M];
    __shared__ float invrs_s[M];
    __shared__ float redA_s[16], redB_s[16], redC_s[16];
    __shared__ float bcast_s[3];

    const int n = blockIdx.x;
    const int t = threadIdx.x;

    STAGE_TABLES();
    STAGE_INPUTS();
    __syncthreads();
    DEF_PLINS();

    // dist-conf / att-conf partials (A recomputed on the fly later)
    float dc_local = 0.f;
    for (int p = t; p < M * M; p += 1024) {
        const int j = p >> 6, k = p & (M - 1);
        PAIR_GEOM(j, k);
        (void)rel;
        dc_local += fabsf(plin(6, dist) - 0.5f);
    }
    const float ac_local = (t < M) ? fabsf(plin(5, att_s[t]) - 0.5f) : 0.f;
    {
        float vA = dc_local, vB = ac_local;
        #pragma unroll
        for (int off = 32; off > 0; off >>= 1) {
            vA += __shfl_down(vA, off, 64);
            vB += __shfl_down(vB, off, 64);
        }
        if ((t & 63) == 0) { redA_s[t >> 6] = vA; redB_s[t >> 6] = vB; }
    }

    // combine the NS partial products, apply att-diff factor
    {
        const int j = t >> 4;
        const int k0 = (t & 15) << 2;
        const float4 v0 = ws4[(n * NS + 0) * 1024 + t];
        const float4 v1 = ws4[(n * NS + 1) * 1024 + t];
        const float4 v2 = ws4[(n * NS + 2) * 1024 + t];
        const float4 v3 = ws4[(n * NS + 3) * 1024 + t];
        const float aj = att_s[j];
        const float s0 = v0.x * v1.x * v2.x * v3.x * plin2d(fabsf(aj - att_s[k0 + 0]));
        const float s1 = v0.y * v1.y * v2.y * v3.y * plin2d(fabsf(aj - att_s[k0 + 1]));
        const float s2 = v0.z * v1.z * v2.z * v3.z * plin2d(fabsf(aj - att_s[k0 + 2]));
        const float s3 = v0.w * v1.w * v2.w * v3.w * plin2d(fabsf(aj - att_s[k0 + 3]));
        *(float4*)&sim_s[j * M + k0] = make_float4(s0, s1, s2, s3);
    }
    __syncthreads();

    // row sums -> invrs
    {
        const int j = t >> 4, c = t & 15;
        float psum = sim_s[j * M + c] + sim_s[j * M + c + 16] +
                     sim_s[j * M + c + 32] + sim_s[j * M + c + 48];
        #pragma unroll
        for (int off = 8; off > 0; off >>= 1) psum += __shfl_down(psum, off, 64);
        if (c == 0) invrs_s[j] = 1.0f / psum;
    }
    __syncthreads();

    // score pass: A computed on the fly
    float sc_local = 0.f;
    for (int p = t; p < M * M; p += 1024) {
        const int j = p >> 6, k = p & (M - 1);
        PAIR_GEOM(j, k);
        sc_local += plin(0, rel) * plin(1, dist) * (invrs_s[j] * invrs_s[k]);
    }
    if (t < M) sc_local += plin(0, att_s[t] * att_s[t]) * invrs_s[t];
    {
        float vC = sc_local;
        #pragma unroll
        for (int off = 32; off > 0; off >>= 1) vC += __shfl_down(vC, off, 64);
        if ((t & 63) == 0) redC_s[t >> 6] = vC;
    }
    __syncthreads();

    if (t == 0) {
        float score_sum = 0.f, dcs = 0.f, acs = 0.f;
        #pragma unroll
        for (int w = 0; w < 16; ++w) { score_sum += redC_s[w]; dcs += redA_s[w]; acs += redB_s[w]; }
        const float score = sqrtf(score_sum + 1e-20f);
        const float conf = plin(7, acs * (1.0f / M) + dcs * (1.0f / (M * M)));
        const float scc = fminf(fmaxf(score, 0.f), 10.0f);
        const float fl = floorf(scc);
        bcast_s[0] = conf; bcast_s[1] = fl; bcast_s[2] = scc - fl;
    }
    __syncthreads();

    if (t < 11) {
        const float conf = bcast_s[0];
        const int i0 = (int)bcast_s[1];
        const float frac = bcast_s[2];
        const int i1 = i0 > 10 ? 10 : i0;
        const int i2 = (i0 + 1) > 10 ? 10 : (i0 + 1);
        float v = 0.f;
        if (t == i1) v += 1.0f - frac;
        if (t == i2) v += frac;
        out[n * 11 + t] = v * conf;
    }
}

extern "C" void kernel_launch(void* const* d_in, const int* in_sizes, int n_in,
                              void* d_out, int out_size, void* d_ws, size_t ws_size,
                              hipStream_t stream) {
    const float* boxes = (const float*)d_in[0];   // (n,4,64) f32
    const float* attn  = (const float*)d_in[1];   // (n,64)   f32
    const float* fw    = (const float*)d_in[2];   // (16,17)  f32
    float* out = (float*)d_out;                   // (n,11)   f32
    const int n = in_sizes[1] / M;
    float4* ws4 = (float4*)d_ws;                  // n*NS*1024 float4 = 8 MB

    k1_partial<<<dim3(n, NS), dim3(1024), 0, stream>>>(boxes, attn, fw, ws4);
    k2_finish<<<dim3(n), dim3(1024), 0, stream>>>(boxes, attn, fw, ws4, out);
}

// Round 8
// 71.911 us; speedup vs baseline: 2.5742x; 1.0839x over previous
//
#include <hip/hip_runtime.h>
#include <math.h>

#define M 64
#define NSEG 16
#define NS 2                 // i-split: 2 blocks per sample, 32-deep each
#define NCHUNK 544           // upper-triangle chunks (j, k0=4*kt), kt >= jt = j/4
#define SSTRIDE 65           // sim LDS row stride (bank spread for mirror writes)

// chunk c -> (j, k0): tile = c>>2 indexes upper-tri of 16x16 (jt<=kt), r = c&3.
// jt = max{g : tile >= T(g)}, T(g) = 16g - g(g-1)/2 (monotone thresholds,
// constants after unroll). FIXES R3/R7 bug: old code compared against a
// DECREASING cum+len after the first miss and spuriously re-fired.
// Hand-verified: c=0->(0,0); tile=15->(r,60); tile=16->(4+r,4);
// tile=30->(4+r,60); tile=31->(8+r,8); tile=135 (c=543)->(60+r,60).
__device__ __forceinline__ void decode_chunk(int c, int& j, int& k0) {
    const int tile = c >> 2;
    const int r = c & 3;
    int jt = 0, cum = 0;
    #pragma unroll
    for (int g = 1; g <= 15; ++g) {
        const int Tg = 16 * g - ((g * (g - 1)) >> 1);
        if (tile >= Tg) { jt = g; cum = Tg; }
    }
    const int kt = jt + (tile - cum);
    j  = (jt << 2) + r;
    k0 = kt << 2;
}

#define STAGE_TABLES()                                                            \
    if (t < 8) {                                                                  \
        float wv[NSEG + 1];                                                       \
        float ssum = 0.f;                                                         \
        _Pragma("unroll")                                                         \
        for (int i = 0; i <= NSEG; ++i) { wv[i] = fabsf(fw[t*(NSEG+1)+i]); ssum += wv[i]; } \
        const float inv = 1.0f / ssum;                                            \
        _Pragma("unroll")                                                         \
        for (int i = 0; i <= NSEG; ++i) wv[i] *= inv;                             \
        float csum = 0.f;                                                         \
        _Pragma("unroll")                                                         \
        for (int i = 0; i <= NSEG; ++i) {                                         \
            csum += wv[i];                                                        \
            cw_s[t][i] = make_float2(csum, wv[i < NSEG ? i + 1 : NSEG]);          \
        }                                                                         \
    }

#define STAGE_INPUTS()                                                            \
    if (t < M) {                                                                  \
        att_s[t] = attn[n * M + t];                                               \
        const float xa = boxes[n*4*M + 0*M + t];                                  \
        const float ya = boxes[n*4*M + 1*M + t];                                  \
        const float xb = boxes[n*4*M + 2*M + t];                                  \
        const float yb = boxes[n*4*M + 3*M + t];                                  \
        x1_s[t] = xa; y1_s[t] = ya; x2_s[t] = xb; y2_s[t] = yb;                   \
        area_s[t] = fmaxf(xb - xa, 0.f) * fmaxf(yb - ya, 0.f);                    \
    }

#define DEF_PLINS()                                                               \
    auto plin = [&](int kk, float x) -> float {                                   \
        const float y = 16.0f * x;                                                \
        const float fi = floorf(y);                                               \
        const int idx = (int)fi;                                                  \
        const float2 cw = cw_s[kk][idx];                                          \
        return cw.x + (y - fi) * cw.y;                                            \
    };                                                                            \
    auto plin2d = [&](float d) -> float {                                         \
        const float y = fmaf(-16.0f, d, 16.0f);                                   \
        int idx = (int)y;                 /* trunc: (-eps) -> 0, in-bounds */     \
        const float fr = y - floorf(y);   /* floor: matches reference frac */     \
        const float2 cw = cw_s[2][idx];                                           \
        return cw.x + fr * cw.y;                                                  \
    };

#define PAIR_GEOM(j_, k_)                                                         \
    const float rel  = att_s[j_] * att_s[k_];                                     \
    const float mx = fmaxf(x1_s[j_], x1_s[k_]);                                   \
    const float my = fmaxf(y1_s[j_], y1_s[k_]);                                   \
    const float Mx = fminf(x2_s[j_], x2_s[k_]);                                   \
    const float My = fminf(y2_s[j_], y2_s[k_]);                                   \
    const float inter = fmaxf(Mx - mx, 0.f) * fmaxf(My - my, 0.f);                \
    const float iou  = inter / (area_s[j_] + area_s[k_] - inter + 1e-12f);        \
    const float dist = 1.0f - iou;

// ---------------- Kernel 1: triangle partial products + (s==0) dist-conf ----------------
__global__ __launch_bounds__(1024, 4)
void k1_partial(const float* __restrict__ boxes,
                const float* __restrict__ attn,
                const float* __restrict__ fw,
                float4* __restrict__ ws4,
                float* __restrict__ ws_dc)
{
    __shared__ float2 cw_s[8][NSEG + 1];
    __shared__ float att_s[M];
    __shared__ float x1_s[M], y1_s[M], x2_s[M], y2_s[M], area_s[M];
    __shared__ float ds_s[M * M];

    const int n = blockIdx.x;
    const int s = blockIdx.y;
    const int t = threadIdx.x;

    STAGE_TABLES();
    STAGE_INPUTS();
    __syncthreads();
    DEF_PLINS();

    // dedup_score matrix (full; needed by all triangle chunks)
    for (int p = t; p < M * M; p += 1024) {
        const int j = p >> 6, k = p & (M - 1);
        PAIR_GEOM(j, k);
        ds_s[p] = plin(3, rel) * plin(4, dist);
    }
    __syncthreads();

    // s==0 block also computes the dist-conf partials (verbatim R4-k2 code)
    if (s == 0) {
        float dc_local = 0.f;
        for (int p = t; p < M * M; p += 1024) {
            const int j = p >> 6, k = p & (M - 1);
            PAIR_GEOM(j, k);
            (void)rel;
            dc_local += fabsf(plin(6, dist) - 0.5f);
        }
        float vA = dc_local;
        #pragma unroll
        for (int off = 32; off > 0; off >>= 1) vA += __shfl_down(vA, off, 64);
        if ((t & 63) == 0) ws_dc[n * 16 + (t >> 6)] = vA;
    }

    // triangle product: chunk t (t<544), 32-deep i in [32s, 32s+32)
    if (t < NCHUNK) {
        int j, k0;
        decode_chunk(t, j, k0);
        const int ibase = s * 32;
        float p0 = 1.f, p1 = 1.f, p2 = 1.f, p3 = 1.f;
        #pragma unroll
        for (int ii = 0; ii < 32; ++ii) {
            const int i = ibase + ii;
            const float aij = ds_s[i * M + j];
            const float4 kv = *(const float4*)&ds_s[i * M + k0];
            p0 *= plin2d(fabsf(aij - kv.x));
            p1 *= plin2d(fabsf(aij - kv.y));
            p2 *= plin2d(fabsf(aij - kv.z));
            p3 *= plin2d(fabsf(aij - kv.w));
        }
        ws4[(n * NS + s) * NCHUNK + t] = make_float4(p0, p1, p2, p3);
    }
}

// ---------------- Kernel 2: combine partials, row sums, score, epilogue ----------------
__global__ __launch_bounds__(1024, 4)
void k2_finish(const float* __restrict__ boxes,
               const float* __restrict__ attn,
               const float* __restrict__ fw,
               const float4* __restrict__ ws4,
               const float* __restrict__ ws_dc,
               float* __restrict__ out)
{
    __shared__ float2 cw_s[8][NSEG + 1];
    __shared__ float att_s[M];
    __shared__ float x1_s[M], y1_s[M], x2_s[M], y2_s[M], area_s[M];
    __shared__ float sim_s[M * SSTRIDE];
    __shared__ float invrs_s[M];
    __shared__ float redB_s[16], redC_s[16];
    __shared__ float bcast_s[3];

    const int n = blockIdx.x;
    const int t = threadIdx.x;

    STAGE_TABLES();
    STAGE_INPUTS();
    __syncthreads();
    DEF_PLINS();

    // att-conf partial (dist-conf comes precomputed from k1 via ws_dc)
    {
        float vB = (t < M) ? fabsf(plin(5, att_s[t]) - 0.5f) : 0.f;
        #pragma unroll
        for (int off = 32; off > 0; off >>= 1) vB += __shfl_down(vB, off, 64);
        if ((t & 63) == 0) redB_s[t >> 6] = vB;
    }

    // combine the NS partial products, apply att factor, scatter direct + mirror
    if (t < NCHUNK) {
        int j, k0;
        decode_chunk(t, j, k0);
        const float4 v0 = ws4[(n * NS + 0) * NCHUNK + t];
        const float4 v1 = ws4[(n * NS + 1) * NCHUNK + t];
        const float aj = att_s[j];
        float sv[4];
        sv[0] = v0.x * v1.x * plin2d(fabsf(aj - att_s[k0 + 0]));
        sv[1] = v0.y * v1.y * plin2d(fabsf(aj - att_s[k0 + 1]));
        sv[2] = v0.z * v1.z * plin2d(fabsf(aj - att_s[k0 + 2]));
        sv[3] = v0.w * v1.w * plin2d(fabsf(aj - att_s[k0 + 3]));
        #pragma unroll
        for (int q = 0; q < 4; ++q) {
            const int k = k0 + q;
            sim_s[j * SSTRIDE + k] = sv[q];   // direct
            sim_s[k * SSTRIDE + j] = sv[q];   // mirror (bit-identical by |a-b| symmetry)
        }
    }
    __syncthreads();

    // row sums -> invrs (same element order as R4)
    {
        const int j = t >> 4, c = t & 15;
        float psum = sim_s[j * SSTRIDE + c] + sim_s[j * SSTRIDE + c + 16] +
                     sim_s[j * SSTRIDE + c + 32] + sim_s[j * SSTRIDE + c + 48];
        #pragma unroll
        for (int off = 8; off > 0; off >>= 1) psum += __shfl_down(psum, off, 64);
        if (c == 0) invrs_s[j] = 1.0f / psum;
    }
    __syncthreads();

    // score pass: A computed on the fly
    float sc_local = 0.f;
    for (int p = t; p < M * M; p += 1024) {
        const int j = p >> 6, k = p & (M - 1);
        PAIR_GEOM(j, k);
        sc_local += plin(0, rel) * plin(1, dist) * (invrs_s[j] * invrs_s[k]);
    }
    if (t < M) sc_local += plin(0, att_s[t] * att_s[t]) * invrs_s[t];
    {
        float vC = sc_local;
        #pragma unroll
        for (int off = 32; off > 0; off >>= 1) vC += __shfl_down(vC, off, 64);
        if ((t & 63) == 0) redC_s[t >> 6] = vC;
    }
    __syncthreads();

    if (t == 0) {
        float score_sum = 0.f, dcs = 0.f, acs = 0.f;
        #pragma unroll
        for (int w = 0; w < 16; ++w) {
            score_sum += redC_s[w];
            dcs += ws_dc[n * 16 + w];     // same order as R4's redA_s sum
            acs += redB_s[w];
        }
        const float score = sqrtf(score_sum + 1e-20f);
        const float conf = plin(7, acs * (1.0f / M) + dcs * (1.0f / (M * M)));
        const float scc = fminf(fmaxf(score, 0.f), 10.0f);
        const float fl = floorf(scc);
        bcast_s[0] = conf; bcast_s[1] = fl; bcast_s[2] = scc - fl;
    }
    __syncthreads();

    if (t < 11) {
        const float conf = bcast_s[0];
        const int i0 = (int)bcast_s[1];
        const float frac = bcast_s[2];
        const int i1 = i0 > 10 ? 10 : i0;
        const int i2 = (i0 + 1) > 10 ? 10 : (i0 + 1);
        float v = 0.f;
        if (t == i1) v += 1.0f - frac;
        if (t == i2) v += frac;
        out[n * 11 + t] = v * conf;
    }
}

extern "C" void kernel_launch(void* const* d_in, const int* in_sizes, int n_in,
                              void* d_out, int out_size, void* d_ws, size_t ws_size,
                              hipStream_t stream) {
    const float* boxes = (const float*)d_in[0];   // (n,4,64) f32
    const float* attn  = (const float*)d_in[1];   // (n,64)   f32
    const float* fw    = (const float*)d_in[2];   // (16,17)  f32
    float* out = (float*)d_out;                   // (n,11)   f32
    const int n = in_sizes[1] / M;

    float4* ws4  = (float4*)d_ws;                           // n*NS*NCHUNK float4 ~ 2.2 MB
    float* ws_dc = (float*)((char*)d_ws + (4u << 20));      // n*16 floats at +4 MB

    k1_partial<<<dim3(n, NS), dim3(1024), 0, stream>>>(boxes, attn, fw, ws4, ws_dc);
    k2_finish<<<dim3(n), dim3(1024), 0, stream>>>(boxes, attn, fw, ws4, ws_dc, out);
}

// Round 9
// 71.232 us; speedup vs baseline: 2.5987x; 1.0095x over previous
//
#include <hip/hip_runtime.h>
#include <math.h>

#define M 64
#define NSEG 16
#define NS 2                 // i-split: 2 blocks per sample, 32-deep each
#define NCHUNK 544           // upper-triangle chunks (j, k0=4*kt), kt >= jt = j/4
#define SSTRIDE 65           // sim LDS row stride (bank spread for mirror writes)

// chunk c -> (j, k0): tile = c>>2 indexes upper-tri of 16x16 (jt<=kt), r = c&3.
// jt = max{g : tile >= T(g)}, T(g) = 16g - g(g-1)/2 (monotone thresholds).
// Hand-verified: c=0->(0,0); tile=15->(r,60); tile=16->(4+r,4);
// tile=30->(4+r,60); tile=31->(8+r,8); tile=135 (c=543)->(60+r,60).
__device__ __forceinline__ void decode_chunk(int c, int& j, int& k0) {
    const int tile = c >> 2;
    const int r = c & 3;
    int jt = 0, cum = 0;
    #pragma unroll
    for (int g = 1; g <= 15; ++g) {
        const int Tg = 16 * g - ((g * (g - 1)) >> 1);
        if (tile >= Tg) { jt = g; cum = Tg; }
    }
    const int kt = jt + (tile - cum);
    j  = (jt << 2) + r;
    k0 = kt << 2;
}

#define STAGE_TABLES()                                                            \
    if (t < 8) {                                                                  \
        float wv[NSEG + 1];                                                       \
        float ssum = 0.f;                                                         \
        _Pragma("unroll")                                                         \
        for (int i = 0; i <= NSEG; ++i) { wv[i] = fabsf(fw[t*(NSEG+1)+i]); ssum += wv[i]; } \
        const float inv = 1.0f / ssum;                                            \
        _Pragma("unroll")                                                         \
        for (int i = 0; i <= NSEG; ++i) wv[i] *= inv;                             \
        float csum = 0.f;                                                         \
        _Pragma("unroll")                                                         \
        for (int i = 0; i <= NSEG; ++i) {                                         \
            csum += wv[i];                                                        \
            cw_s[t][i] = make_float2(csum, wv[i < NSEG ? i + 1 : NSEG]);          \
        }                                                                         \
    }

#define STAGE_INPUTS()                                                            \
    if (t < M) {                                                                  \
        att_s[t] = attn[n * M + t];                                               \
        const float xa = boxes[n*4*M + 0*M + t];                                  \
        const float ya = boxes[n*4*M + 1*M + t];                                  \
        const float xb = boxes[n*4*M + 2*M + t];                                  \
        const float yb = boxes[n*4*M + 3*M + t];                                  \
        x1_s[t] = xa; y1_s[t] = ya; x2_s[t] = xb; y2_s[t] = yb;                   \
        area_s[t] = fmaxf(xb - xa, 0.f) * fmaxf(yb - ya, 0.f);                    \
    }

#define DEF_PLINS()                                                               \
    auto plin = [&](int kk, float x) -> float {                                   \
        const float y = 16.0f * x;                                                \
        const float fi = floorf(y);                                               \
        const int idx = (int)fi;                                                  \
        const float2 cw = cw_s[kk][idx];                                          \
        return cw.x + (y - fi) * cw.y;                                            \
    };                                                                            \
    auto plin2d = [&](float d) -> float {                                         \
        const float y = fmaf(-16.0f, d, 16.0f);                                   \
        int idx = (int)y;                 /* trunc: (-eps) -> 0, in-bounds */     \
        const float fr = y - floorf(y);   /* floor: matches reference frac */     \
        const float2 cw = cw_s[2][idx];                                           \
        return cw.x + fr * cw.y;                                                  \
    };

#define PAIR_GEOM(j_, k_)                                                         \
    const float rel  = att_s[j_] * att_s[k_];                                     \
    const float mx = fmaxf(x1_s[j_], x1_s[k_]);                                   \
    const float my = fmaxf(y1_s[j_], y1_s[k_]);                                   \
    const float Mx = fminf(x2_s[j_], x2_s[k_]);                                   \
    const float My = fminf(y2_s[j_], y2_s[k_]);                                   \
    const float inter = fmaxf(Mx - mx, 0.f) * fmaxf(My - my, 0.f);                \
    const float iou  = inter / (area_s[j_] + area_s[k_] - inter + 1e-12f);        \
    const float dist = 1.0f - iou;

// ---- Kernel 1: half-staging (own i-rows) + A matrix + dist-conf + triangle products ----
__global__ __launch_bounds__(1024, 4)
void k1_partial(const float* __restrict__ boxes,
                const float* __restrict__ attn,
                const float* __restrict__ fw,
                float4* __restrict__ ws4,
                float* __restrict__ ws_a,
                float* __restrict__ ws_dc)
{
    __shared__ float2 cw_s[8][NSEG + 1];
    __shared__ float att_s[M];
    __shared__ float x1_s[M], y1_s[M], x2_s[M], y2_s[M], area_s[M];
    __shared__ float ds_s[32 * M];   // only this block's 32 i-rows

    const int n = blockIdx.x;
    const int s = blockIdx.y;
    const int t = threadIdx.x;

    STAGE_TABLES();
    STAGE_INPUTS();
    __syncthreads();
    DEF_PLINS();

    // stage only pairs (i,k) with i in [32s, 32s+32): ds rows + A + dist-conf
    float dc_local = 0.f;
    #pragma unroll
    for (int it = 0; it < 2; ++it) {
        const int p2 = it * 1024 + t;          // 0..2047 local pair
        const int p  = s * 2048 + p2;          // global pair
        const int i  = p >> 6, k = p & (M - 1);
        PAIR_GEOM(i, k);
        ds_s[p2] = plin(3, rel) * plin(4, dist);
        ws_a[n * (M * M) + p] = plin(0, rel) * plin(1, dist);
        dc_local += fabsf(plin(6, dist) - 0.5f);
    }
    {
        float vA = dc_local;
        #pragma unroll
        for (int off = 32; off > 0; off >>= 1) vA += __shfl_down(vA, off, 64);
        if ((t & 63) == 0) ws_dc[n * 32 + s * 16 + (t >> 6)] = vA;
    }
    __syncthreads();

    // triangle product: chunk t (t<544), 32-deep i in local rows [0,32)
    if (t < NCHUNK) {
        int j, k0;
        decode_chunk(t, j, k0);
        float p0 = 1.f, p1 = 1.f, p2 = 1.f, p3 = 1.f;
        #pragma unroll
        for (int ii = 0; ii < 32; ++ii) {
            const float aij = ds_s[ii * M + j];
            const float4 kv = *(const float4*)&ds_s[ii * M + k0];
            p0 *= plin2d(fabsf(aij - kv.x));
            p1 *= plin2d(fabsf(aij - kv.y));
            p2 *= plin2d(fabsf(aij - kv.z));
            p3 *= plin2d(fabsf(aij - kv.w));
        }
        ws4[(n * NS + s) * NCHUNK + t] = make_float4(p0, p1, p2, p3);
    }
}

// ---- Kernel 2: combine partials, row sums, score from precomputed A, epilogue ----
__global__ __launch_bounds__(1024, 4)
void k2_finish(const float* __restrict__ attn,
               const float* __restrict__ fw,
               const float4* __restrict__ ws4,
               const float* __restrict__ ws_a,
               const float* __restrict__ ws_dc,
               float* __restrict__ out)
{
    __shared__ float2 cw_s[8][NSEG + 1];
    __shared__ float att_s[M];
    __shared__ float sim_s[M * SSTRIDE];
    __shared__ float invrs_s[M];
    __shared__ float redB_s[16], redC_s[16];
    __shared__ float bcast_s[3];

    const int n = blockIdx.x;
    const int t = threadIdx.x;

    STAGE_TABLES();
    if (t < M) att_s[t] = attn[n * M + t];
    __syncthreads();
    DEF_PLINS();

    // att-conf partial
    {
        float vB = (t < M) ? fabsf(plin(5, att_s[t]) - 0.5f) : 0.f;
        #pragma unroll
        for (int off = 32; off > 0; off >>= 1) vB += __shfl_down(vB, off, 64);
        if ((t & 63) == 0) redB_s[t >> 6] = vB;
    }

    // combine the NS partial products, apply att factor, scatter direct + mirror
    if (t < NCHUNK) {
        int j, k0;
        decode_chunk(t, j, k0);
        const float4 v0 = ws4[(n * NS + 0) * NCHUNK + t];
        const float4 v1 = ws4[(n * NS + 1) * NCHUNK + t];
        const float aj = att_s[j];
        float sv[4];
        sv[0] = v0.x * v1.x * plin2d(fabsf(aj - att_s[k0 + 0]));
        sv[1] = v0.y * v1.y * plin2d(fabsf(aj - att_s[k0 + 1]));
        sv[2] = v0.z * v1.z * plin2d(fabsf(aj - att_s[k0 + 2]));
        sv[3] = v0.w * v1.w * plin2d(fabsf(aj - att_s[k0 + 3]));
        #pragma unroll
        for (int q = 0; q < 4; ++q) {
            const int k = k0 + q;
            sim_s[j * SSTRIDE + k] = sv[q];   // direct
            sim_s[k * SSTRIDE + j] = sv[q];   // mirror (bit-identical by |a-b| symmetry)
        }
    }
    __syncthreads();

    // row sums -> invrs
    {
        const int j = t >> 4, c = t & 15;
        float psum = sim_s[j * SSTRIDE + c] + sim_s[j * SSTRIDE + c + 16] +
                     sim_s[j * SSTRIDE + c + 32] + sim_s[j * SSTRIDE + c + 48];
        #pragma unroll
        for (int off = 8; off > 0; off >>= 1) psum += __shfl_down(psum, off, 64);
        if (c == 0) invrs_s[j] = 1.0f / psum;
    }
    __syncthreads();

    // score pass: A precomputed by k1 (L2-resident, coalesced)
    float sc_local = 0.f;
    #pragma unroll
    for (int it = 0; it < 4; ++it) {
        const int p = it * 1024 + t;
        sc_local += ws_a[n * (M * M) + p] * (invrs_s[p >> 6] * invrs_s[p & (M - 1)]);
    }
    if (t < M) sc_local += plin(0, att_s[t] * att_s[t]) * invrs_s[t];
    {
        float vC = sc_local;
        #pragma unroll
        for (int off = 32; off > 0; off >>= 1) vC += __shfl_down(vC, off, 64);
        if ((t & 63) == 0) redC_s[t >> 6] = vC;
    }
    __syncthreads();

    if (t == 0) {
        float score_sum = 0.f, dcs = 0.f, acs = 0.f;
        #pragma unroll
        for (int w = 0; w < 16; ++w) { score_sum += redC_s[w]; acs += redB_s[w]; }
        #pragma unroll
        for (int w = 0; w < 32; ++w) dcs += ws_dc[n * 32 + w];
        const float score = sqrtf(score_sum + 1e-20f);
        const float conf = plin(7, acs * (1.0f / M) + dcs * (1.0f / (M * M)));
        const float scc = fminf(fmaxf(score, 0.f), 10.0f);
        const float fl = floorf(scc);
        bcast_s[0] = conf; bcast_s[1] = fl; bcast_s[2] = scc - fl;
    }
    __syncthreads();

    if (t < 11) {
        const float conf = bcast_s[0];
        const int i0 = (int)bcast_s[1];
        const float frac = bcast_s[2];
        const int i1 = i0 > 10 ? 10 : i0;
        const int i2 = (i0 + 1) > 10 ? 10 : (i0 + 1);
        float v = 0.f;
        if (t == i1) v += 1.0f - frac;
        if (t == i2) v += frac;
        out[n * 11 + t] = v * conf;
    }
}

extern "C" void kernel_launch(void* const* d_in, const int* in_sizes, int n_in,
                              void* d_out, int out_size, void* d_ws, size_t ws_size,
                              hipStream_t stream) {
    const float* boxes = (const float*)d_in[0];   // (n,4,64) f32
    const float* attn  = (const float*)d_in[1];   // (n,64)   f32
    const float* fw    = (const float*)d_in[2];   // (16,17)  f32
    float* out = (float*)d_out;                   // (n,11)   f32
    const int n = in_sizes[1] / M;

    float4* ws4  = (float4*)d_ws;                           // n*NS*NCHUNK float4 ~ 2.2 MB
    float* ws_a  = (float*)((char*)d_ws + (4u << 20));      // n*4096 floats = 2 MB at +4 MB
    float* ws_dc = (float*)((char*)d_ws + (8u << 20));      // n*32 floats at +8 MB

    k1_partial<<<dim3(n, NS), dim3(1024), 0, stream>>>(boxes, attn, fw, ws4, ws_a, ws_dc);
    k2_finish<<<dim3(n), dim3(1024), 0, stream>>>(attn, fw, ws4, ws_a, ws_dc, out);
}